// Round 1
// baseline (200.394 us; speedup 1.0000x reference)
//
#include <hip/hip_runtime.h>

#define NB 32      // batch
#define NJ 8192    // h*w*Nin
#define DIN 8
#define NC 10      // NUM_CAPS
#define CL 16      // CAP_LEN
#define KK 160     // NC*CL
#define JT 32      // j-tile per block
#define NT 320     // threads per block (5 waves)

// One routing iteration, fused: recompute u, (softmax weights), partial-s.
// R=0: c uniform 0.1, vsum unused. R>0: logits b_r = u . vsum (linearity of
// the agreement update lets us carry only vsum = v0+...+v_{r-1}).
template<int R>
__global__ __launch_bounds__(NT)
void rout_kernel(const float* __restrict__ x, const float* __restrict__ W,
                 const float* __restrict__ vsum, float* __restrict__ s_out) {
    __shared__ float xs[JT][DIN];        // 1 KB
    __shared__ float us[JT][KK + 4];     // ~21 KB, +4 pad vs bank conflicts
    __shared__ float vs[KK];
    __shared__ float bl[JT][NC];
    __shared__ float cl[JT][NC];

    const int b  = blockIdx.x;           // b fastest -> same-jtile blocks adjacent (W L2/LLC reuse)
    const int j0 = blockIdx.y * JT;
    const int t  = threadIdx.x;

    if (t < JT * DIN)
        xs[t / DIN][t % DIN] = x[(size_t)(b * NJ + j0) * DIN + t];
    if (R > 0 && t < KK)
        vs[t] = vsum[b * KK + t];
    __syncthreads();

    // ---- phase 1: u[jj][k] = sum_i xs[jj][i] * W[j0+jj][i][k] ----
    {
        const int k  = t % KK;
        const int jp = t / KK;           // 0 or 1
        for (int jj = jp; jj < JT; jj += 2) {
            const float* wp = W + (size_t)(j0 + jj) * (DIN * KK) + k;
            float acc = 0.f;
            #pragma unroll
            for (int i = 0; i < DIN; ++i)
                acc = fmaf(xs[jj][i], wp[i * KK], acc);
            us[jj][k] = acc;
        }
    }
    __syncthreads();

    if (R > 0) {
        // ---- phase 2: logits + softmax over n (exactly 320 = 32j x 10n) ----
        const int j = t / NC;
        const int n = t - j * NC;
        float bd = 0.f;
        #pragma unroll
        for (int c = 0; c < CL; ++c)
            bd = fmaf(us[j][n * CL + c], vs[n * CL + c], bd);
        bl[j][n] = bd;
        __syncthreads();
        float m = -1e30f;
        #pragma unroll
        for (int nn = 0; nn < NC; ++nn) m = fmaxf(m, bl[j][nn]);
        float sum = 0.f;
        #pragma unroll
        for (int nn = 0; nn < NC; ++nn) sum += __expf(bl[j][nn] - m);
        cl[j][n] = __expf(bd - m) / sum;
        __syncthreads();
    }

    // ---- phase 3: s[b][k] += sum_jj c[jj][n(k)] * u[jj][k] ----
    if (t < KK) {
        const int n = t / CL;
        float acc = 0.f;
        #pragma unroll
        for (int jj = 0; jj < JT; ++jj) {
            const float c = (R == 0) ? 0.1f : cl[jj][n];
            acc = fmaf(c, us[jj][t], acc);
        }
        atomicAdd(&s_out[b * KK + t], acc);
    }
}

// v = squash(s + bias); FINAL: write d_out, else accumulate into vsum.
template<bool FINAL>
__global__ void squash_kernel(const float* __restrict__ s,
                              const float* __restrict__ biases,
                              float* __restrict__ vdst) {
    const int t = blockIdx.x * blockDim.x + threadIdx.x;
    if (t >= NB * KK) return;
    const float val = s[t] + biases[t % KK];
    const float n = fabsf(val);
    const float v = (n * n) / (1.f + n * n) / (n + 1e-20f) * val;
    if (FINAL) vdst[t] = v;
    else       vdst[t] += v;
}

extern "C" void kernel_launch(void* const* d_in, const int* in_sizes, int n_in,
                              void* d_out, int out_size, void* d_ws, size_t ws_size,
                              hipStream_t stream) {
    const float* x      = (const float*)d_in[0];
    const float* W      = (const float*)d_in[1];
    const float* biases = (const float*)d_in[2];
    float* out  = (float*)d_out;
    float* s    = (float*)d_ws;          // [NB*KK]
    float* vsum = s + NB * KK;           // [NB*KK]

    hipMemsetAsync(d_ws, 0, 2 * NB * KK * sizeof(float), stream);

    dim3 grid(NB, NJ / JT);
    rout_kernel<0><<<grid, NT, 0, stream>>>(x, W, nullptr, s);
    squash_kernel<false><<<(NB * KK + 255) / 256, 256, 0, stream>>>(s, biases, vsum);

    hipMemsetAsync(s, 0, NB * KK * sizeof(float), stream);
    rout_kernel<1><<<grid, NT, 0, stream>>>(x, W, vsum, s);
    squash_kernel<false><<<(NB * KK + 255) / 256, 256, 0, stream>>>(s, biases, vsum);

    hipMemsetAsync(s, 0, NB * KK * sizeof(float), stream);
    rout_kernel<2><<<grid, NT, 0, stream>>>(x, W, vsum, s);
    squash_kernel<true><<<(NB * KK + 255) / 256, 256, 0, stream>>>(s, biases, out);
}

// Round 2
// 165.823 us; speedup vs baseline: 1.2085x; 1.2085x over previous
//
#include <hip/hip_runtime.h>

#define NB 32      // batch
#define NJ 8192    // h*w*Nin
#define NC 10      // NUM_CAPS
#define CL 16      // CAP_LEN
#define KK 160     // NC*CL
#define JT 16      // j per block
#define NTHR 640   // 16 jj x 40 k4
#define REP 8      // s_part replicas (atomic contention spread)
#define USW 204    // us row stride in words (10 caps * 20 + 4 pad)
#define VSW 200    // vsl row stride in words
#define EPSQ 1e-20f

// One routing iteration. W cached in registers (32 VGPR/thread), b-loop inside.
// Linearity trick: logits b_r[b,j,n] = u . (v0+...+v_{r-1}), so only vsum is carried.
template<int R>
__global__ __launch_bounds__(NTHR, 5)
void rout_kernel(const float* __restrict__ x, const float* __restrict__ W,
                 const float* __restrict__ vsum, float* __restrict__ s_part) {
    __shared__ float xs[NB][JT][8];    // 16 KB
    __shared__ float us[JT * USW];     // 13.1 KB (k mapped as n*20 + c)
    __shared__ float vsl[NB * VSW];    // 25.6 KB (k mapped as n*20 + c)
    __shared__ float bl[JT][12];
    __shared__ float cl[JT][12];

    const int t    = threadIdx.x;
    const int j0   = blockIdx.x * JT;
    const int jj_w = t / 40;           // this thread's j within tile
    const int k4   = t % 40;           // float4 chunk of k (k = 4*k4..4*k4+3)
    const int nB   = k4 >> 2;          // cap index n for this k-quad
    const int c4B  = k4 & 3;           // c-quad within cap
    const int rep  = blockIdx.x & (REP - 1);

    // ---- W -> registers, read exactly once per dispatch ----
    float4 w[8];
    {
        const float* wp = W + ((size_t)(j0 + jj_w) * 8) * KK + (k4 << 2);
        #pragma unroll
        for (int i = 0; i < 8; ++i)
            w[i] = *(const float4*)(wp + (size_t)i * KK);
    }
    // ---- x tile -> LDS (all 32 batches) ----
    for (int e4 = t; e4 < NB * JT * 2; e4 += NTHR) {
        const int b = e4 >> 5, rem = e4 & 31, jj = rem >> 1, hf = rem & 1;
        *(float4*)&xs[b][jj][hf * 4] =
            *(const float4*)(x + (((size_t)b * NJ) + j0 + jj) * 8 + (size_t)hf * 4);
    }
    // ---- vsum -> LDS, padded layout (R>0 only) ----
    if (R > 0) {
        for (int f4 = t; f4 < NB * 40; f4 += NTHR) {
            const int b = f4 / 40, rem = f4 % 40;
            *(float4*)&vsl[b * VSW + (rem >> 2) * 20 + (rem & 3) * 4] =
                *(const float4*)(vsum + (size_t)b * KK + (size_t)rem * 4);
        }
    }
    __syncthreads();

    for (int b = 0; b < NB; ++b) {
        // ---- A: u quad in registers, stash to LDS for phase D ----
        const float4 xa = *(const float4*)&xs[b][jj_w][0];
        const float4 xb = *(const float4*)&xs[b][jj_w][4];
        const float xi[8] = {xa.x, xa.y, xa.z, xa.w, xb.x, xb.y, xb.z, xb.w};
        float4 u; u.x = 0.f; u.y = 0.f; u.z = 0.f; u.w = 0.f;
        #pragma unroll
        for (int i = 0; i < 8; ++i) {
            u.x = fmaf(w[i].x, xi[i], u.x);
            u.y = fmaf(w[i].y, xi[i], u.y);
            u.z = fmaf(w[i].z, xi[i], u.z);
            u.w = fmaf(w[i].w, xi[i], u.w);
        }
        *(float4*)&us[jj_w * USW + nB * 20 + c4B * 4] = u;

        if (R > 0) {
            // ---- B: logit partial from OWN registers + 4-lane shfl reduce ----
            const float4 vv = *(const float4*)&vsl[b * VSW + nB * 20 + c4B * 4];
            float bd = u.x * vv.x + u.y * vv.y + u.z * vv.z + u.w * vv.w;
            bd += __shfl_xor(bd, 1);
            bd += __shfl_xor(bd, 2);
            if (c4B == 0) bl[jj_w][nB] = bd;
            __syncthreads();
            // ---- C: softmax over n (160 threads) ----
            if (t < JT * NC) {
                const int jjC = t / NC, nn = t - jjC * NC;
                float m = -1e30f;
                #pragma unroll
                for (int q = 0; q < NC; ++q) m = fmaxf(m, bl[jjC][q]);
                float sum = 0.f;
                #pragma unroll
                for (int q = 0; q < NC; ++q) sum += __expf(bl[jjC][q] - m);
                cl[jjC][nn] = __expf(bl[jjC][nn] - m) / sum;
            }
            __syncthreads();
        } else {
            __syncthreads();   // us visible for D
        }

        // ---- D: s[b][k] partial over this block's 16 jj ----
        {
            const int kD = t >> 2, jjc = t & 3;
            const int nD = kD >> 4, cD = kD & 15;
            float sv = 0.f;
            #pragma unroll
            for (int q = 0; q < 4; ++q) {
                const int jj = jjc * 4 + q;
                const float c = (R == 0) ? 0.1f : cl[jj][nD];
                sv = fmaf(c, us[jj * USW + nD * 20 + cD], sv);
            }
            sv += __shfl_xor(sv, 1);
            sv += __shfl_xor(sv, 2);
            if (jjc == 0)
                atomicAdd(&s_part[(size_t)rep * (NB * KK) + b * KK + kD], sv);
        }
        __syncthreads();       // protect us before next b overwrites
    }
}

// Sum replicas, +bias, squash. MODE: 0 vsum=v, 1 vsum+=v, 2 out=v. Re-zeroes s_part.
template<int MODE>
__global__ __launch_bounds__(640)
void squash_kernel(float* __restrict__ s_part, const float* __restrict__ biases,
                   float* __restrict__ vsum, float* __restrict__ out) {
    const int t = blockIdx.x * blockDim.x + threadIdx.x;   // 0..5119
    float s = 0.f;
    #pragma unroll
    for (int r = 0; r < REP; ++r) {
        s += s_part[(size_t)r * (NB * KK) + t];
        s_part[(size_t)r * (NB * KK) + t] = 0.f;
    }
    s += biases[t % KK];
    const float n = fabsf(s);
    const float v = (n * n) / (1.f + n * n) / (n + EPSQ) * s;
    if (MODE == 2)      out[t]   = v;
    else if (MODE == 1) vsum[t] += v;
    else                vsum[t]  = v;
}

extern "C" void kernel_launch(void* const* d_in, const int* in_sizes, int n_in,
                              void* d_out, int out_size, void* d_ws, size_t ws_size,
                              hipStream_t stream) {
    const float* x      = (const float*)d_in[0];
    const float* W      = (const float*)d_in[1];
    const float* biases = (const float*)d_in[2];
    float* out    = (float*)d_out;
    float* s_part = (float*)d_ws;                  // [REP][NB*KK]
    float* vsum   = s_part + (size_t)REP * NB * KK; // [NB*KK]

    hipMemsetAsync(s_part, 0, (size_t)REP * NB * KK * sizeof(float), stream);

    const dim3 grid(NJ / JT);   // 512
    rout_kernel<0><<<grid, NTHR, 0, stream>>>(x, W, nullptr, s_part);
    squash_kernel<0><<<8, 640, 0, stream>>>(s_part, biases, vsum, out);

    rout_kernel<1><<<grid, NTHR, 0, stream>>>(x, W, vsum, s_part);
    squash_kernel<1><<<8, 640, 0, stream>>>(s_part, biases, vsum, out);

    rout_kernel<2><<<grid, NTHR, 0, stream>>>(x, W, vsum, s_part);
    squash_kernel<2><<<8, 640, 0, stream>>>(s_part, biases, vsum, out);
}